// Round 1
// baseline (766.291 us; speedup 1.0000x reference)
//
#include <hip/hip_runtime.h>

#define EMBED 64
#define SCAN_THREADS 256
#define SCAN_ITEMS 16
#define SCAN_TILE (SCAN_THREADS * SCAN_ITEMS)  // 4096

__global__ void zero_ints(int* __restrict__ p, int n) {
    int i = blockIdx.x * blockDim.x + threadIdx.x;
    if (i < n) p[i] = 0;
}

__global__ void hist_rows(const int* __restrict__ row, int* __restrict__ deg, int nnz) {
    int stride = gridDim.x * blockDim.x;
    for (int i = blockIdx.x * blockDim.x + threadIdx.x; i < nnz; i += stride)
        atomicAdd(&deg[row[i]], 1);
}

// Per-tile exclusive scan: writes tile-local exclusive prefix + tile sums.
__global__ void scan_tiles(const int* __restrict__ deg, int* __restrict__ offs,
                           int* __restrict__ tile_sums, int n) {
    __shared__ int sh[SCAN_THREADS];
    int t = threadIdx.x;
    int base = blockIdx.x * SCAN_TILE + t * SCAN_ITEMS;
    int vals[SCAN_ITEMS];
    int sum = 0;
#pragma unroll
    for (int k = 0; k < SCAN_ITEMS; ++k) {
        int idx = base + k;
        vals[k] = (idx < n) ? deg[idx] : 0;
        sum += vals[k];
    }
    sh[t] = sum;
    __syncthreads();
    for (int off = 1; off < SCAN_THREADS; off <<= 1) {
        int v = (t >= off) ? sh[t - off] : 0;
        __syncthreads();
        sh[t] += v;
        __syncthreads();
    }
    int excl = sh[t] - sum;
    if (t == SCAN_THREADS - 1) tile_sums[blockIdx.x] = sh[t];
    int run = excl;
#pragma unroll
    for (int k = 0; k < SCAN_ITEMS; ++k) {
        int idx = base + k;
        if (idx < n) offs[idx] = run;
        run += vals[k];
    }
}

__global__ void scan_bases(const int* __restrict__ tile_sums, int* __restrict__ tile_base,
                           int ntiles) {
    if (threadIdx.x == 0 && blockIdx.x == 0) {
        int run = 0;
        for (int i = 0; i < ntiles; ++i) { tile_base[i] = run; run += tile_sums[i]; }
        tile_base[ntiles] = run;
    }
}

__global__ void add_bases(int* __restrict__ offs, int* __restrict__ cursors,
                          const int* __restrict__ tile_base, int n, int ntiles) {
    int i = blockIdx.x * blockDim.x + threadIdx.x;
    if (i < n) {
        int v = offs[i] + tile_base[i / SCAN_TILE];
        offs[i] = v;
        cursors[i] = v;
    }
    if (i == 0) offs[n] = tile_base[ntiles];
}

__global__ void scatter_edges(const int* __restrict__ row, const int* __restrict__ col,
                              const float* __restrict__ vals, int* __restrict__ cursors,
                              int* __restrict__ ecol, float* __restrict__ eval, int nnz) {
    int stride = gridDim.x * blockDim.x;
    for (int i = blockIdx.x * blockDim.x + threadIdx.x; i < nnz; i += stride) {
        int r = row[i];
        int slot = atomicAdd(&cursors[r], 1);
        ecol[slot] = col[i];
        eval[slot] = vals[i];
    }
}

__global__ void concat_copy(const float* __restrict__ ue, const float* __restrict__ ie,
                            float* __restrict__ x, int nu4, int tot4) {
    int stride = gridDim.x * blockDim.x;
    for (int i = blockIdx.x * blockDim.x + threadIdx.x; i < tot4; i += stride) {
        float4 v = (i < nu4) ? ((const float4*)ue)[i] : ((const float4*)ie)[i - nu4];
        ((float4*)x)[i] = v;
    }
}

// One wave per node; 4 edge-groups x 16 lanes x float4; shuffle-reduce across groups.
__global__ __launch_bounds__(256) void spmm(const int* __restrict__ offs,
                                            const int* __restrict__ ecol,
                                            const float* __restrict__ eval,
                                            const float* __restrict__ x,
                                            float* __restrict__ y, int n_nodes) {
    int wave = blockIdx.x * (blockDim.x >> 6) + (threadIdx.x >> 6);
    if (wave >= n_nodes) return;
    int lane = threadIdx.x & 63;
    int g = lane >> 4;    // edge subgroup 0..3
    int l16 = lane & 15;  // dim-quad
    int start = offs[wave];
    int end = offs[wave + 1];
    float4 acc = make_float4(0.f, 0.f, 0.f, 0.f);
    for (int e = start + g; e < end; e += 4) {
        int c = ecol[e];
        float v = eval[e];
        float4 xv = *(const float4*)(x + (size_t)c * EMBED + l16 * 4);
        acc.x += v * xv.x;
        acc.y += v * xv.y;
        acc.z += v * xv.z;
        acc.w += v * xv.w;
    }
#pragma unroll
    for (int m = 16; m <= 32; m <<= 1) {
        acc.x += __shfl_xor(acc.x, m);
        acc.y += __shfl_xor(acc.y, m);
        acc.z += __shfl_xor(acc.z, m);
        acc.w += __shfl_xor(acc.w, m);
    }
    if (g == 0)
        *(float4*)(y + (size_t)wave * EMBED + l16 * 4) = acc;
}

__global__ void gather_out(const float* __restrict__ x, const int* __restrict__ users,
                           const int* __restrict__ pos, const int* __restrict__ neg,
                           float* __restrict__ out, int batch, int n_users, int first) {
    int idx = blockIdx.x * blockDim.x + threadIdx.x;
    int total = 3 * batch * EMBED;
    if (idx >= total) return;
    int r = idx >> 6;
    int d = idx & 63;
    int which = r / batch;
    int b = r - which * batch;
    int node = (which == 0) ? users[b] : ((which == 1) ? (n_users + pos[b]) : (n_users + neg[b]));
    float v = 0.25f * x[(size_t)node * EMBED + d];
    if (first) out[idx] = v;
    else out[idx] += v;
}

extern "C" void kernel_launch(void* const* d_in, const int* in_sizes, int n_in,
                              void* d_out, int out_size, void* d_ws, size_t ws_size,
                              hipStream_t stream) {
    const float* user_emb = (const float*)d_in[0];
    const float* item_emb = (const float*)d_in[1];
    const int* row = (const int*)d_in[2];
    const int* col = (const int*)d_in[3];
    const float* vals = (const float*)d_in[4];
    const int* users = (const int*)d_in[5];
    const int* pos = (const int*)d_in[6];
    const int* neg = (const int*)d_in[7];
    float* out = (float*)d_out;

    int n_users = in_sizes[0] / EMBED;
    int n_items = in_sizes[1] / EMBED;
    int n_nodes = n_users + n_items;
    int nnz = in_sizes[2];
    int batch = in_sizes[5];

    char* p = (char*)d_ws;
    auto alloc = [&](size_t bytes) -> void* {
        void* r = (void*)p;
        p += (bytes + 255) & ~(size_t)255;
        return r;
    };
    int ntiles = (n_nodes + SCAN_TILE - 1) / SCAN_TILE;
    int* deg = (int*)alloc(sizeof(int) * (size_t)n_nodes);
    int* offs = (int*)alloc(sizeof(int) * (size_t)(n_nodes + 1));
    int* cursors = (int*)alloc(sizeof(int) * (size_t)n_nodes);
    int* tile_sums = (int*)alloc(sizeof(int) * (size_t)ntiles);
    int* tile_base = (int*)alloc(sizeof(int) * (size_t)(ntiles + 1));
    int* ecol = (int*)alloc(sizeof(int) * (size_t)nnz);
    float* eval = (float*)alloc(sizeof(float) * (size_t)nnz);
    float* bufA = (float*)alloc(sizeof(float) * (size_t)n_nodes * EMBED);
    float* bufB = (float*)alloc(sizeof(float) * (size_t)n_nodes * EMBED);
    if ((size_t)(p - (char*)d_ws) > ws_size) return;  // workspace too small: bail visibly

    zero_ints<<<(n_nodes + 255) / 256, 256, 0, stream>>>(deg, n_nodes);
    hist_rows<<<2048, 256, 0, stream>>>(row, deg, nnz);
    scan_tiles<<<ntiles, SCAN_THREADS, 0, stream>>>(deg, offs, tile_sums, n_nodes);
    scan_bases<<<1, 64, 0, stream>>>(tile_sums, tile_base, ntiles);
    add_bases<<<(n_nodes + 255) / 256, 256, 0, stream>>>(offs, cursors, tile_base, n_nodes, ntiles);
    scatter_edges<<<2048, 256, 0, stream>>>(row, col, vals, cursors, ecol, eval, nnz);

    int tot4 = n_nodes * EMBED / 4;
    int nu4 = n_users * EMBED / 4;
    concat_copy<<<2048, 256, 0, stream>>>(user_emb, item_emb, bufA, nu4, tot4);

    int gblocks = (3 * batch * EMBED + 255) / 256;
    int spmm_blocks = (n_nodes + 3) / 4;

    gather_out<<<gblocks, 256, 0, stream>>>(bufA, users, pos, neg, out, batch, n_users, 1);
    spmm<<<spmm_blocks, 256, 0, stream>>>(offs, ecol, eval, bufA, bufB, n_nodes);
    gather_out<<<gblocks, 256, 0, stream>>>(bufB, users, pos, neg, out, batch, n_users, 0);
    spmm<<<spmm_blocks, 256, 0, stream>>>(offs, ecol, eval, bufB, bufA, n_nodes);
    gather_out<<<gblocks, 256, 0, stream>>>(bufA, users, pos, neg, out, batch, n_users, 0);
    spmm<<<spmm_blocks, 256, 0, stream>>>(offs, ecol, eval, bufA, bufB, n_nodes);
    gather_out<<<gblocks, 256, 0, stream>>>(bufB, users, pos, neg, out, batch, n_users, 0);
}